// Round 9
// baseline (1659.550 us; speedup 1.0000x reference)
//
#include <hip/hip_runtime.h>
#include <math.h>

typedef __attribute__((ext_vector_type(8))) short bf16x8;
typedef __attribute__((ext_vector_type(4))) float f32x4;

static __device__ __forceinline__ short f2bf(float f) {
    unsigned u = __float_as_uint(f);
    unsigned r = (u + 0x7fffu + ((u >> 16) & 1u)) >> 16;
    return (short)r;
}
static __device__ __forceinline__ float bf2f(short s) {
    return __uint_as_float(((unsigned)(unsigned short)s) << 16);
}
static __device__ __forceinline__ float bflo(int v) { return bf2f((short)(v & 0xffff)); }
static __device__ __forceinline__ float bfhi(int v) { return bf2f((short)(((unsigned)v) >> 16)); }
static __device__ __forceinline__ int pack2(float a, float b) {
    return (int)(((unsigned)(unsigned short)f2bf(b) << 16) | (unsigned)(unsigned short)f2bf(a));
}

// ---------------- zero fill ----------------
__global__ void zero_i32_k(int* __restrict__ p, int n) {
    int i = blockIdx.x * 256 + threadIdx.x;
    if (i < n) p[i] = 0;
}

// ---------------- weight convert+transpose: W[K x Nc] fp32 -> Wt[Nc x K] bf16 ----------------
__global__ __launch_bounds__(256) void wconv_k(const float* __restrict__ W, short* __restrict__ Wt,
                                               int K, int Nc) {
    int slice = blockIdx.y;
    const float* src = W + (size_t)slice * K * Nc;
    short* dst = Wt + (size_t)slice * K * Nc;
    int idx = blockIdx.x * 256 + threadIdx.x;
    if (idx >= K * Nc) return;
    int k = idx / Nc, n = idx - k * Nc;
    dst[(size_t)n * K + k] = f2bf(src[idx]);
}

// ---------------- embed: u = relu(x@W1+b1), h = x@Ws+bs (both bf16) ----------------
__global__ __launch_bounds__(256) void embed_k(
    const float* __restrict__ x, const float* __restrict__ W1, const float* __restrict__ b1,
    const float* __restrict__ Ws, const float* __restrict__ bs,
    int* __restrict__ u2, int* __restrict__ h2, int Nn)
{
    int idx = blockIdx.x * 256 + threadIdx.x;
    if (idx >= Nn * 64) return;
    int n = idx >> 6, c = (idx & 63) * 2;
    float x0 = x[2*n], x1 = x[2*n+1];
    float u0 = fmaxf(fmaf(x1, W1[128+c],   fmaf(x0, W1[c],   b1[c])),   0.f);
    float u1 = fmaxf(fmaf(x1, W1[128+c+1], fmaf(x0, W1[c+1], b1[c+1])), 0.f);
    float h0 = fmaf(x1, Ws[128+c],   fmaf(x0, Ws[c],   bs[c]));
    float h1 = fmaf(x1, Ws[128+c+1], fmaf(x0, Ws[c+1], bs[c+1]));
    u2[idx] = pack2(u0, u1);
    h2[idx] = pack2(h0, h1);
}

// ------- bf16 MFMA GEMM v4: BARRIER-FREE main loop -------
// A and B fragments both loaded directly from global in MFMA layout
// (B rows Wt[col][k] are L2-resident; no LDS staging, no main-loop barriers).
// K = NK*128, A given as NK chunk base pointers (row stride Astr shorts).
// C bf16 [Nrows x ldC]; BETA: += (Rres ? Rres : C); RELU on output.
// ELR: also emit el/er per-head dots (z-GEMM only).
// LDS used only for the output transpose (1 barrier); row stride 132 shorts
// (66 words ≡ 2 mod 32 -> 2-way bank aliasing = free), 8B reads.
template<int NK, int RELU, int BETA, int ELR>
__global__ __launch_bounds__(256) void gemm3_k(
    const short* __restrict__ A0, const short* __restrict__ A1,
    const short* __restrict__ A2, const short* __restrict__ A3,
    const short* __restrict__ A4, int Astr,
    const short* __restrict__ Wt, int ldWt,
    const float* __restrict__ bias, short* __restrict__ C, const short* __restrict__ Rres,
    int Nrows, int ldC,
    const float* __restrict__ al, const float* __restrict__ ar,
    float* __restrict__ elo, float* __restrict__ ero)
{
    __shared__ short Cs[128][132];
    const int row0 = blockIdx.x * 128;
    const int col0 = blockIdx.y * 128;
    const int t = threadIdx.x;
    const int w = t >> 6, lane = t & 63, q = lane >> 4, m = lane & 15;

    f32x4 acc[2][8];
    #pragma unroll
    for (int rb = 0; rb < 2; ++rb)
        #pragma unroll
        for (int cb = 0; cb < 8; ++cb)
            acc[rb][cb] = (f32x4){0.f, 0.f, 0.f, 0.f};

    const short* Asrc[5] = {A0, A1, A2, A3, A4};
    int rr0 = row0 + w*32 + m;      if (rr0 > Nrows - 1) rr0 = Nrows - 1;
    int rr1 = row0 + w*32 + 16 + m; if (rr1 > Nrows - 1) rr1 = Nrows - 1;

    // B fragment row pointers (L2-resident weight rows)
    const short* pb[8];
    #pragma unroll
    for (int cb = 0; cb < 8; ++cb)
        pb[cb] = Wt + (size_t)(col0 + cb * 16 + m) * ldWt + q * 8;

    #pragma unroll
    for (int kh = 0; kh < NK; ++kh) {
        const short* pa0 = Asrc[kh] + (size_t)rr0 * Astr + q * 8;
        const short* pa1 = Asrc[kh] + (size_t)rr1 * Astr + q * 8;
        // prefetch all A fragments of this chunk
        bf16x8 af0[4], af1[4];
        #pragma unroll
        for (int ks = 0; ks < 4; ++ks) {
            af0[ks] = *(const bf16x8*)(pa0 + ks * 32);
            af1[ks] = *(const bf16x8*)(pa1 + ks * 32);
        }
        #pragma unroll
        for (int ks = 0; ks < 4; ++ks) {
            bf16x8 bfr[8];
            #pragma unroll
            for (int cb = 0; cb < 8; ++cb)
                bfr[cb] = *(const bf16x8*)(pb[cb] + kh * 128 + ks * 32);
            #pragma unroll
            for (int cb = 0; cb < 8; ++cb) {
                acc[0][cb] = __builtin_amdgcn_mfma_f32_16x16x32_bf16(af0[ks], bfr[cb], acc[0][cb], 0, 0, 0);
                acc[1][cb] = __builtin_amdgcn_mfma_f32_16x16x32_bf16(af1[ks], bfr[cb], acc[1][cb], 0, 0, 0);
            }
        }
    }

    // ---- epilogue: stage bf16 tile in LDS (transpose), coalesced stores ----
    #pragma unroll
    for (int rb = 0; rb < 2; ++rb) {
        #pragma unroll
        for (int r = 0; r < 4; ++r) {
            int lrow = w * 32 + rb * 16 + q * 4 + r;
            #pragma unroll
            for (int cb = 0; cb < 8; ++cb) {
                float v = acc[rb][cb][r];
                if (bias) v += bias[col0 + cb * 16 + m];
                if (RELU) v = fmaxf(v, 0.f);
                Cs[lrow][cb * 16 + m] = f2bf(v);
            }
        }
    }
    __syncthreads();
    const short* Rd = Rres ? Rres : C;
    int r2 = t >> 1;
    int cbase = (t & 1) * 64;
    int grow = row0 + r2;
    if (grow < Nrows) {
        size_t gb = (size_t)grow * ldC + col0 + cbase;
        float elv[8], erv[8];
        #pragma unroll
        for (int j = 0; j < 8; ++j) {
            int2 lo8 = *(const int2*)&Cs[r2][cbase + j * 8];
            int2 hi8 = *(const int2*)&Cs[r2][cbase + j * 8 + 4];
            int4 cv = make_int4(lo8.x, lo8.y, hi8.x, hi8.y);
            if (BETA) {
                int4 rv = *(const int4*)(Rd + gb + j * 8);
                int* cp = (int*)&cv; const int* rp = (const int*)&rv;
                #pragma unroll
                for (int e = 0; e < 4; ++e) {
                    float lo = bflo(cp[e]) + bflo(rp[e]);
                    float hi = bfhi(cp[e]) + bfhi(rp[e]);
                    cp[e] = pack2(lo, hi);
                }
            }
            if (ELR) {
                const float* alp = al + cbase + j * 8;
                const float* arp = ar + cbase + j * 8;
                const int* cp = (const int*)&cv;
                float sl = 0.f, sr = 0.f;
                #pragma unroll
                for (int e = 0; e < 4; ++e) {
                    float lo = bflo(cp[e]), hi = bfhi(cp[e]);
                    sl = fmaf(lo, alp[2*e], sl); sl = fmaf(hi, alp[2*e+1], sl);
                    sr = fmaf(lo, arp[2*e], sr); sr = fmaf(hi, arp[2*e+1], sr);
                }
                elv[j] = sl; erv[j] = sr;
            }
            *(int4*)(C + gb + j * 8) = cv;
        }
        if (ELR) {
            float* ep = elo + (size_t)grow * 16 + (t & 1) * 8;
            float* rp = ero + (size_t)grow * 16 + (t & 1) * 8;
            *(float4*)ep       = make_float4(elv[0], elv[1], elv[2], elv[3]);
            *(float4*)(ep + 4) = make_float4(elv[4], elv[5], elv[6], elv[7]);
            *(float4*)rp       = make_float4(erv[0], erv[1], erv[2], erv[3]);
            *(float4*)(rp + 4) = make_float4(erv[4], erv[5], erv[6], erv[7]);
        }
    }
}

// ---------------- CSR build ----------------
__global__ void count_k(const int* __restrict__ dst, int* __restrict__ cnt, int E) {
    int e = blockIdx.x * 256 + threadIdx.x;
    if (e < E) atomicAdd(&cnt[dst[e]], 1);
}

__global__ __launch_bounds__(256) void scan_part_k(const int* __restrict__ cnt,
                                                   int* __restrict__ bsum, int Nn) {
    __shared__ int red[256];
    int base = blockIdx.x * 1024;
    int s = 0;
    for (int i = threadIdx.x; i < 1024; i += 256) {
        int g = base + i;
        if (g < Nn) s += cnt[g];
    }
    red[threadIdx.x] = s; __syncthreads();
    for (int off = 128; off; off >>= 1) {
        if ((int)threadIdx.x < off) red[threadIdx.x] += red[threadIdx.x + off];
        __syncthreads();
    }
    if (threadIdx.x == 0) bsum[blockIdx.x] = red[0];
}

__global__ __launch_bounds__(256) void scan_top_k(int* __restrict__ bsum, int nb) {
    __shared__ int buf[256];
    int v = ((int)threadIdx.x < nb) ? bsum[threadIdx.x] : 0;
    buf[threadIdx.x] = v; __syncthreads();
    for (int off = 1; off < 256; off <<= 1) {
        int tv = ((int)threadIdx.x >= off) ? buf[threadIdx.x - off] : 0;
        __syncthreads();
        buf[threadIdx.x] += tv;
        __syncthreads();
    }
    if ((int)threadIdx.x < nb) bsum[threadIdx.x] = buf[threadIdx.x] - v;
}

__global__ __launch_bounds__(256) void scan_fin_k(const int* __restrict__ cnt,
    const int* __restrict__ bsum, int* __restrict__ rowptr, int* __restrict__ wpos, int Nn)
{
    __shared__ int tsum[256];
    int base = blockIdx.x * 1024;
    int g0 = base + (int)threadIdx.x * 4;
    int v[4]; int s = 0;
    #pragma unroll
    for (int j = 0; j < 4; ++j) {
        int g = g0 + j;
        v[j] = (g < Nn) ? cnt[g] : 0;
        s += v[j];
    }
    tsum[threadIdx.x] = s; __syncthreads();
    for (int off = 1; off < 256; off <<= 1) {
        int tv = ((int)threadIdx.x >= off) ? tsum[threadIdx.x - off] : 0;
        __syncthreads();
        tsum[threadIdx.x] += tv;
        __syncthreads();
    }
    int run = bsum[blockIdx.x] + tsum[threadIdx.x] - s;
    #pragma unroll
    for (int j = 0; j < 4; ++j) {
        int g = g0 + j;
        if (g < Nn) { wpos[g] = run; rowptr[g + 1] = run + v[j]; }
        run += v[j];
    }
    if (blockIdx.x == 0 && threadIdx.x == 0) rowptr[0] = 0;
}

__global__ void scatter_k(const int* __restrict__ src, const int* __restrict__ dst,
                          int* __restrict__ wpos, int* __restrict__ esrc, int E) {
    int e = blockIdx.x * 256 + threadIdx.x;
    if (e < E) {
        int p = atomicAdd(&wpos[dst[e]], 1);
        esrc[p] = src[e];
    }
}

// ---------------- GAT aggregate: online softmax, one wave per node, unroll x4 ----------------
__global__ __launch_bounds__(256) void gat_k(
    const short* __restrict__ h, const short* __restrict__ z,
    const float* __restrict__ el, const float* __restrict__ er,
    const int* __restrict__ rowptr, const int* __restrict__ esrc,
    const float* __restrict__ gbias, short* __restrict__ t1, int Nn)
{
    int gw = (blockIdx.x * 256 + threadIdx.x) >> 6;
    if (gw >= Nn) return;
    int lane = threadIdx.x & 63;
    int c = lane * 2;
    int head = lane >> 2;
    float ern = er[gw*16 + head];
    int beg = rowptr[gw], end = rowptr[gw+1];
    float m = -3.0e38f, den = 0.f, a0 = 0.f, a1 = 0.f;
    int i = beg;
    for (; i + 3 < end; i += 4) {
        int s0 = esrc[i], s1 = esrc[i+1], s2 = esrc[i+2], s3 = esrc[i+3];
        float e0 = el[s0*16 + head] + ern;
        float e1 = el[s1*16 + head] + ern;
        float e2 = el[s2*16 + head] + ern;
        float e3 = el[s3*16 + head] + ern;
        int zz0 = *(const int*)(z + (size_t)s0*128 + c);
        int zz1 = *(const int*)(z + (size_t)s1*128 + c);
        int zz2 = *(const int*)(z + (size_t)s2*128 + c);
        int zz3 = *(const int*)(z + (size_t)s3*128 + c);
        e0 = (e0 > 0.f) ? e0 : 0.2f * e0;
        e1 = (e1 > 0.f) ? e1 : 0.2f * e1;
        e2 = (e2 > 0.f) ? e2 : 0.2f * e2;
        e3 = (e3 > 0.f) ? e3 : 0.2f * e3;
        float nm = fmaxf(fmaxf(fmaxf(e0, e1), fmaxf(e2, e3)), m);
        float sc = __expf(m - nm);
        float w0 = __expf(e0 - nm), w1 = __expf(e1 - nm);
        float w2 = __expf(e2 - nm), w3 = __expf(e3 - nm);
        den = fmaf(den, sc, (w0 + w1) + (w2 + w3));
        a0 = fmaf(a0, sc, fmaf(w0, bflo(zz0), fmaf(w1, bflo(zz1), fmaf(w2, bflo(zz2), w3 * bflo(zz3)))));
        a1 = fmaf(a1, sc, fmaf(w0, bfhi(zz0), fmaf(w1, bfhi(zz1), fmaf(w2, bfhi(zz2), w3 * bfhi(zz3)))));
        m = nm;
    }
    for (; i + 1 < end; i += 2) {
        int s0 = esrc[i], s1 = esrc[i+1];
        float e0 = el[s0*16 + head] + ern;
        float e1 = el[s1*16 + head] + ern;
        int zz0 = *(const int*)(z + (size_t)s0*128 + c);
        int zz1 = *(const int*)(z + (size_t)s1*128 + c);
        e0 = (e0 > 0.f) ? e0 : 0.2f * e0;
        e1 = (e1 > 0.f) ? e1 : 0.2f * e1;
        float nm = fmaxf(m, fmaxf(e0, e1));
        float sc = __expf(m - nm);
        float w0 = __expf(e0 - nm);
        float w1 = __expf(e1 - nm);
        den = fmaf(den, sc, w0 + w1);
        a0  = fmaf(a0, sc, fmaf(w0, bflo(zz0), w1 * bflo(zz1)));
        a1  = fmaf(a1, sc, fmaf(w0, bfhi(zz0), w1 * bfhi(zz1)));
        m = nm;
    }
    if (i < end) {
        int s0 = esrc[i];
        float e0 = el[s0*16 + head] + ern;
        int zz0 = *(const int*)(z + (size_t)s0*128 + c);
        e0 = (e0 > 0.f) ? e0 : 0.2f * e0;
        float nm = fmaxf(m, e0);
        float sc = __expf(m - nm);
        float w0 = __expf(e0 - nm);
        den = fmaf(den, sc, w0);
        a0  = fmaf(a0, sc, w0 * bflo(zz0));
        a1  = fmaf(a1, sc, w0 * bfhi(zz0));
    }
    float inv = 1.f / den;
    size_t o = (size_t)gw*64 + lane;
    int hv = ((const int*)h)[o];
    float r0 = bflo(hv) + a0*inv + gbias[c];
    float r1 = bfhi(hv) + a1*inv + gbias[c+1];
    ((int*)t1)[o] = pack2(r0, r1);
}

// ---------------- BatchNorm (bf16 in, fp32 stats) ----------------
__global__ __launch_bounds__(256) void bn_stats_k(const short* __restrict__ xin,
    float* __restrict__ stats, int Nn)
{
    __shared__ float s0s[256], s1s[256], q0s[256], q1s[256];
    int pair = threadIdx.x & 63;
    int slot = threadIdx.x >> 6;
    float s0 = 0.f, s1 = 0.f, q0 = 0.f, q1 = 0.f;
    for (int r = blockIdx.x*4 + slot; r < Nn; r += gridDim.x*4) {
        int v = *(const int*)(xin + (size_t)r*128 + pair*2);
        float a = bflo(v), b = bfhi(v);
        s0 += a; s1 += b;
        q0 = fmaf(a, a, q0); q1 = fmaf(b, b, q1);
    }
    s0s[threadIdx.x] = s0; s1s[threadIdx.x] = s1;
    q0s[threadIdx.x] = q0; q1s[threadIdx.x] = q1;
    __syncthreads();
    if (slot == 0) {
        #pragma unroll
        for (int j = 1; j < 4; ++j) {
            s0 += s0s[pair + j*64]; s1 += s1s[pair + j*64];
            q0 += q0s[pair + j*64]; q1 += q1s[pair + j*64];
        }
        atomicAdd(&stats[pair*2],       s0);
        atomicAdd(&stats[pair*2+1],     s1);
        atomicAdd(&stats[128+pair*2],   q0);
        atomicAdd(&stats[128+pair*2+1], q1);
    }
}

__global__ __launch_bounds__(256) void bn_apply_k(const short* __restrict__ xin,
    const float* __restrict__ stats, const float* __restrict__ g, const float* __restrict__ b,
    short* __restrict__ hout, int Nn)
{
    int idx = blockIdx.x * 256 + threadIdx.x;
    if (idx >= Nn * 64) return;
    int c = (idx & 63) * 2;
    float invN = 1.f / (float)Nn;
    float mu0 = stats[c] * invN,   mu1 = stats[c+1] * invN;
    float v0 = stats[128+c] * invN - mu0*mu0;
    float v1 = stats[128+c+1] * invN - mu1*mu1;
    float sc0 = rsqrtf(v0 + 1e-5f) * g[c],   sc1 = rsqrtf(v1 + 1e-5f) * g[c+1];
    int v = ((const int*)xin)[idx];
    float y0 = (bflo(v) - mu0) * sc0 + b[c];
    float y1 = (bfhi(v) - mu1) * sc1 + b[c+1];
    ((int*)hout)[idx] = pack2(y0, y1);
}

// ---------------- decoder output ----------------
__global__ __launch_bounds__(256) void dec_out_k(const short* __restrict__ udec,
    const float* __restrict__ W2, const float* __restrict__ b2,
    float* __restrict__ out, int Nn)
{
    int gw = (blockIdx.x * 256 + threadIdx.x) >> 6;
    if (gw >= Nn) return;
    int lane = threadIdx.x & 63;
    int v = ((const int*)(udec + (size_t)gw * 128))[lane];
    float p = bflo(v) * W2[lane*2] + bfhi(v) * W2[lane*2 + 1];
    #pragma unroll
    for (int off = 32; off > 0; off >>= 1) p += __shfl_down(p, off);
    if (lane == 0) out[gw] = p + b2[0];
}

extern "C" void kernel_launch(void* const* d_in, const int* in_sizes, int n_in,
                              void* d_out, int out_size, void* d_ws, size_t ws_size,
                              hipStream_t stream)
{
    const float* x      = (const float*)d_in[0];
    const int*   src    = (const int*)  d_in[1];
    const int*   dst    = (const int*)  d_in[2];
    const float* emb_W1 = (const float*)d_in[3];
    const float* emb_b1 = (const float*)d_in[4];
    const float* emb_W2 = (const float*)d_in[5];
    const float* emb_b2 = (const float*)d_in[6];
    const float* emb_Ws = (const float*)d_in[7];
    const float* emb_bs = (const float*)d_in[8];
    const float* gat_W  = (const float*)d_in[9];
    const float* gat_al = (const float*)d_in[10];
    const float* gat_ar = (const float*)d_in[11];
    const float* gat_b  = (const float*)d_in[12];
    const float* bn1_g  = (const float*)d_in[13];
    const float* bn1_b  = (const float*)d_in[14];
    const float* ff_W1  = (const float*)d_in[15];
    const float* ff_b1  = (const float*)d_in[16];
    const float* ff_W2  = (const float*)d_in[17];
    const float* ff_b2  = (const float*)d_in[18];
    const float* bn2_g  = (const float*)d_in[19];
    const float* bn2_b  = (const float*)d_in[20];
    const float* dec_W1 = (const float*)d_in[21];
    const float* dec_b1 = (const float*)d_in[22];
    const float* dec_W2 = (const float*)d_in[23];
    const float* dec_b2 = (const float*)d_in[24];
    float* out = (float*)d_out;
    (void)n_in; (void)out_size;

    const int N = in_sizes[0] / 2;
    const int E = in_sizes[1];

    // ---- workspace (~235 MB) ----
    char* p = (char*)d_ws;
    size_t used = 0;
    auto carve = [&](size_t bytes) {
        char* r = p; size_t a = (bytes + 255) & ~(size_t)255;
        p += a; used += a; return r;
    };
    const size_t nbH = (size_t)N * 128 * 2;   // one bf16 feature map
    short* xs[5];
    for (int i = 0; i < 5; ++i) xs[i] = (short*)carve(nbH);
    short* hmid = (short*)carve(nbH);
    short* t1   = (short*)carve(nbH);
    char*  big  = (char*)carve(2 * nbH);      // u / (z | el | er) / ffh / udec
    int*   cnt    = (int*)carve((size_t)N * 4);
    float* stats8 = (float*)carve(8 * 256 * 4);   // adjacent to cnt: zeroed together
    int*   rowptr = (int*)carve((size_t)(N + 1) * 4);
    int*   wpos   = (int*)carve((size_t)N * 4);
    int*   esrc   = (int*)carve((size_t)E * 4);
    int*   bsum   = (int*)carve(256 * 4);
    short* emb_W2t = (short*)carve((size_t)128 * 128 * 2);
    short* gat_Wt  = (short*)carve((size_t)4 * 128 * 128 * 2);
    short* ff_W1t  = (short*)carve((size_t)4 * 128 * 256 * 2);
    short* ff_W2t  = (short*)carve((size_t)4 * 256 * 128 * 2);
    short* dec_W1t = (short*)carve((size_t)640 * 128 * 2);
    if (used > ws_size) return;

    short* u    = (short*)big;                    // embed phase
    short* z    = (short*)big;                    // GAT phase
    float* el   = (float*)(big + nbH);            // GAT phase
    float* er   = el + (size_t)N * 16;
    short* ffh  = (short*)big;                    // FF phase (N x 256)
    short* udec = (short*)big;                    // decoder phase

    dim3 b256(256);
    int ecb  = (E + 255) / 256;
    int nel2 = (N * 64 + 255) / 256;
    int gx   = (N + 127) / 128;
    int nwv  = (N + 3) / 4;
    int nb   = (N + 1023) / 1024;

    // ---- weight convert + transpose ----
    wconv_k<<<dim3(64, 1), b256, 0, stream>>>(emb_W2, emb_W2t, 128, 128);
    wconv_k<<<dim3(64, 4), b256, 0, stream>>>(gat_W,  gat_Wt,  128, 128);
    wconv_k<<<dim3(128, 4), b256, 0, stream>>>(ff_W1, ff_W1t,  128, 256);
    wconv_k<<<dim3(128, 4), b256, 0, stream>>>(ff_W2, ff_W2t,  256, 128);
    wconv_k<<<dim3(320, 1), b256, 0, stream>>>(dec_W1, dec_W1t, 640, 128);

    // ---- zero cnt + 8 BN stats buffers (contiguous) ----
    {
        int ztot = (int)(((char*)(stats8 + 8*256) - (char*)cnt) / 4);
        zero_i32_k<<<(ztot + 255) / 256, b256, 0, stream>>>(cnt, ztot);
    }

    // ---- CSR build ----
    count_k<<<ecb, b256, 0, stream>>>(dst, cnt, E);
    scan_part_k<<<nb, b256, 0, stream>>>(cnt, bsum, N);
    scan_top_k<<<1, b256, 0, stream>>>(bsum, nb);
    scan_fin_k<<<nb, b256, 0, stream>>>(cnt, bsum, rowptr, wpos, N);
    scatter_k<<<ecb, b256, 0, stream>>>(src, dst, wpos, esrc, E);

    // ---- embed: xs0 = relu(x@W1+b1)@W2 + b2 + (x@Ws+bs) ----
    embed_k<<<nel2, b256, 0, stream>>>(x, emb_W1, emb_b1, emb_Ws, emb_bs, (int*)u, (int*)xs[0], N);
    gemm3_k<1,0,1,0><<<dim3(gx,1), b256, 0, stream>>>(u,u,u,u,u, 128, emb_W2t, 128,
        emb_b2, xs[0], nullptr, N, 128, nullptr, nullptr, nullptr, nullptr);

    for (int l = 0; l < 4; ++l) {
        float* st1 = stats8 + (size_t)(l*2)   * 256;
        float* st2 = stats8 + (size_t)(l*2+1) * 256;
        short* hl = xs[l];
        // z = xs[l] @ gatW[l]  (+ fused el/er)
        gemm3_k<1,0,0,1><<<dim3(gx,1), b256, 0, stream>>>(hl,hl,hl,hl,hl, 128,
            gat_Wt + (size_t)l*128*128, 128, nullptr, z, nullptr, N, 128,
            gat_al + l*128, gat_ar + l*128, el, er);
        gat_k<<<nwv, b256, 0, stream>>>(hl, z, el, er, rowptr, esrc, gat_b + l*128, t1, N);
        bn_stats_k<<<400, b256, 0, stream>>>(t1, st1, N);
        bn_apply_k<<<nel2, b256, 0, stream>>>(t1, st1, bn1_g + l*128, bn1_b + l*128, hmid, N);
        // FF: ffh = relu(hmid@W1+b1); t1 = hmid + ffh@W2 + b2
        gemm3_k<1,1,0,0><<<dim3(gx,2), b256, 0, stream>>>(hmid,hmid,hmid,hmid,hmid, 128,
            ff_W1t + (size_t)l*128*256, 128, ff_b1 + l*256, ffh, nullptr, N, 256,
            nullptr, nullptr, nullptr, nullptr);
        gemm3_k<2,0,1,0><<<dim3(gx,1), b256, 0, stream>>>(ffh, ffh + 128, ffh, ffh, ffh, 256,
            ff_W2t + (size_t)l*256*128, 256, ff_b2 + l*128, t1, hmid, N, 128,
            nullptr, nullptr, nullptr, nullptr);
        bn_stats_k<<<400, b256, 0, stream>>>(t1, st2, N);
        bn_apply_k<<<nel2, b256, 0, stream>>>(t1, st2, bn2_g + l*128, bn2_b + l*128, xs[l+1], N);
    }

    // ---- decoder: udec = relu(concat(xs) @ dec_W1 + b1)  (virtual concat, K=640) ----
    gemm3_k<5,1,0,0><<<dim3(gx,1), b256, 0, stream>>>(xs[0], xs[1], xs[2], xs[3], xs[4], 128,
        dec_W1t, 640, dec_b1, udec, nullptr, N, 128,
        nullptr, nullptr, nullptr, nullptr);
    dec_out_k<<<nwv, b256, 0, stream>>>(udec, dec_W2, dec_b2, out, N);
}

// Round 10
// 1146.460 us; speedup vs baseline: 1.4475x; 1.4475x over previous
//
#include <hip/hip_runtime.h>
#include <math.h>

typedef __attribute__((ext_vector_type(8))) short bf16x8;
typedef __attribute__((ext_vector_type(4))) float f32x4;

struct BN5 {
    const float* st[5];
    const float* g[5];
    const float* b[5];
    const float* stR;
    const float* gR;
    const float* bR;
    float invN;
};

static __device__ __forceinline__ short f2bf(float f) {
    unsigned u = __float_as_uint(f);
    unsigned r = (u + 0x7fffu + ((u >> 16) & 1u)) >> 16;
    return (short)r;
}
static __device__ __forceinline__ float bf2f(short s) {
    return __uint_as_float(((unsigned)(unsigned short)s) << 16);
}
static __device__ __forceinline__ float bflo(int v) { return bf2f((short)(v & 0xffff)); }
static __device__ __forceinline__ float bfhi(int v) { return bf2f((short)(((unsigned)v) >> 16)); }
static __device__ __forceinline__ int pack2(float a, float b) {
    return (int)(((unsigned)(unsigned short)f2bf(b) << 16) | (unsigned)(unsigned short)f2bf(a));
}

// ---------------- zero fill ----------------
__global__ void zero_i32_k(int* __restrict__ p, int n) {
    int i = blockIdx.x * 256 + threadIdx.x;
    if (i < n) p[i] = 0;
}

// ---------------- weight convert+transpose ----------------
__global__ __launch_bounds__(256) void wconv_k(const float* __restrict__ W, short* __restrict__ Wt,
                                               int K, int Nc) {
    int slice = blockIdx.y;
    const float* src = W + (size_t)slice * K * Nc;
    short* dst = Wt + (size_t)slice * K * Nc;
    int idx = blockIdx.x * 256 + threadIdx.x;
    if (idx >= K * Nc) return;
    int k = idx / Nc, n = idx - k * Nc;
    dst[(size_t)n * K + k] = f2bf(src[idx]);
}

// ---------------- embed ----------------
__global__ __launch_bounds__(256) void embed_k(
    const float* __restrict__ x, const float* __restrict__ W1, const float* __restrict__ b1,
    const float* __restrict__ Ws, const float* __restrict__ bs,
    int* __restrict__ u2, int* __restrict__ h2, int Nn)
{
    int idx = blockIdx.x * 256 + threadIdx.x;
    if (idx >= Nn * 64) return;
    int n = idx >> 6, c = (idx & 63) * 2;
    float x0 = x[2*n], x1 = x[2*n+1];
    float u0 = fmaxf(fmaf(x1, W1[128+c],   fmaf(x0, W1[c],   b1[c])),   0.f);
    float u1 = fmaxf(fmaf(x1, W1[128+c+1], fmaf(x0, W1[c+1], b1[c+1])), 0.f);
    float h0 = fmaf(x1, Ws[128+c],   fmaf(x0, Ws[c],   bs[c]));
    float h1 = fmaf(x1, Ws[128+c+1], fmaf(x0, Ws[c+1], bs[c+1]));
    u2[idx] = pack2(u0, u1);
    h2[idx] = pack2(h0, h1);
}

// ------- bf16 MFMA GEMM (R8 structure + fused BN/stats, fixed epilogue) -------
// B staged in LDS per 128-k chunk; A fragments prefetched to registers pre-barrier,
// with optional per-chunk BatchNorm applied on the fly (bn.st[kh] != null).
// BETA: += residual (Rres or C), optionally BN'd via bn.stR (single col-block only).
// ELR: emit el/er per-head dots. STATS: accumulate output channel sums into statsOut.
template<int NK, int RELU, int BETA, int ELR, int STATS>
__global__ __launch_bounds__(256) void gemm2_k(
    const short* __restrict__ A0, const short* __restrict__ A1,
    const short* __restrict__ A2, const short* __restrict__ A3,
    const short* __restrict__ A4, int Astr,
    const short* __restrict__ Wt, int ldWt,
    const float* __restrict__ bias, short* __restrict__ C, const short* __restrict__ Rres,
    int Nrows, int ldC, BN5 bn,
    const float* __restrict__ al, const float* __restrict__ ar,
    float* __restrict__ elo, float* __restrict__ ero,
    float* __restrict__ statsOut)
{
    __shared__ short Bs[128][136];   // staging view (stride 136)
    const int row0 = blockIdx.x * 128;
    const int col0 = blockIdx.y * 128;
    const int t = threadIdx.x;
    const int w = t >> 6, lane = t & 63, q = lane >> 4, m = lane & 15;

    f32x4 acc[2][8];
    #pragma unroll
    for (int rb = 0; rb < 2; ++rb)
        #pragma unroll
        for (int cb = 0; cb < 8; ++cb)
            acc[rb][cb] = (f32x4){0.f, 0.f, 0.f, 0.f};

    const short* Asrc[5] = {A0, A1, A2, A3, A4};
    int rr0 = row0 + w*32 + m;      if (rr0 > Nrows - 1) rr0 = Nrows - 1;
    int rr1 = row0 + w*32 + 16 + m; if (rr1 > Nrows - 1) rr1 = Nrows - 1;

    #pragma unroll
    for (int kh = 0; kh < NK; ++kh) {
        if (kh) __syncthreads();
        #pragma unroll
        for (int it = 0; it < 8; ++it) {
            int ci = t + it * 256;
            int r = ci >> 4, j = (ci & 15) * 8;
            *(int4*)&Bs[r][j] = *(const int4*)(Wt + (size_t)(col0 + r) * ldWt + kh * 128 + j);
        }
        const short* pa0 = Asrc[kh] + (size_t)rr0 * Astr + q * 8;
        const short* pa1 = Asrc[kh] + (size_t)rr1 * Astr + q * 8;
        bf16x8 af0[4], af1[4];
        #pragma unroll
        for (int ks = 0; ks < 4; ++ks) {
            af0[ks] = *(const bf16x8*)(pa0 + ks * 32);
            af1[ks] = *(const bf16x8*)(pa1 + ks * 32);
        }
        if (bn.st[kh]) {   // fused BatchNorm on A fragments (wave-uniform branch)
            const float* st = bn.st[kh];
            const float* gg = bn.g[kh];
            const float* bb = bn.b[kh];
            #pragma unroll
            for (int ks = 0; ks < 4; ++ks) {
                #pragma unroll
                for (int e = 0; e < 8; ++e) {
                    int c = ks * 32 + q * 8 + e;
                    float mu = st[c] * bn.invN;
                    float var = st[128 + c] * bn.invN - mu * mu;
                    float sc = rsqrtf(var + 1e-5f) * gg[c];
                    float bc = bb[c] - mu * sc;
                    af0[ks][e] = f2bf(fmaf(bf2f(af0[ks][e]), sc, bc));
                    af1[ks][e] = f2bf(fmaf(bf2f(af1[ks][e]), sc, bc));
                }
            }
        }
        __syncthreads();
        #pragma unroll
        for (int ks = 0; ks < 4; ++ks) {
            bf16x8 bfr[8];
            #pragma unroll
            for (int cb = 0; cb < 8; ++cb)
                bfr[cb] = *(const bf16x8*)&Bs[cb * 16 + m][ks * 32 + q * 8];
            #pragma unroll
            for (int cb = 0; cb < 8; ++cb) {
                acc[0][cb] = __builtin_amdgcn_mfma_f32_16x16x32_bf16(af0[ks], bfr[cb], acc[0][cb], 0, 0, 0);
                acc[1][cb] = __builtin_amdgcn_mfma_f32_16x16x32_bf16(af1[ks], bfr[cb], acc[1][cb], 0, 0, 0);
            }
        }
    }

    // ---- epilogue: LDS transpose (stride 132 view: 66 words = 2 mod 32 -> free) ----
    __syncthreads();
    short* Cs = (short*)Bs;
    #pragma unroll
    for (int rb = 0; rb < 2; ++rb) {
        #pragma unroll
        for (int r = 0; r < 4; ++r) {
            int lrow = w * 32 + rb * 16 + q * 4 + r;
            #pragma unroll
            for (int cb = 0; cb < 8; ++cb) {
                float v = acc[rb][cb][r];
                if (bias) v += bias[col0 + cb * 16 + m];
                if (RELU) v = fmaxf(v, 0.f);
                Cs[lrow * 132 + cb * 16 + m] = f2bf(v);
            }
        }
    }
    __syncthreads();
    // thread t -> chunk (t&15), row group (t>>4); each store instr = 4 full rows
    const int chunk = t & 15, rgrp = t >> 4, cb8 = chunk * 8;
    const short* Rd = Rres ? Rres : C;
    float scR[8], bbR[8];
    if (BETA) {
        if (bn.stR) {
            #pragma unroll
            for (int e = 0; e < 8; ++e) {
                int c = cb8 + e;
                float mu = bn.stR[c] * bn.invN;
                float var = bn.stR[128 + c] * bn.invN - mu * mu;
                float sc = rsqrtf(var + 1e-5f) * bn.gR[c];
                scR[e] = sc; bbR[e] = bn.bR[c] - mu * sc;
            }
        }
    }
    float sS[8], sQ[8];
    if (STATS) {
        #pragma unroll
        for (int e = 0; e < 8; ++e) { sS[e] = 0.f; sQ[e] = 0.f; }
    }
    #pragma unroll
    for (int j = 0; j < 8; ++j) {
        int r = rgrp + j * 16;
        int grow = row0 + r;
        if (grow < Nrows) {
            int2 u0 = *(const int2*)(Cs + r * 132 + cb8);
            int2 u1 = *(const int2*)(Cs + r * 132 + cb8 + 4);
            int4 cv = make_int4(u0.x, u0.y, u1.x, u1.y);
            size_t gb = (size_t)grow * ldC + col0 + cb8;
            if (BETA) {
                int4 rv = *(const int4*)(Rd + gb);
                int* cp = (int*)&cv; const int* rp = (const int*)&rv;
                #pragma unroll
                for (int e = 0; e < 4; ++e) {
                    float rlo = bflo(rp[e]), rhi = bfhi(rp[e]);
                    if (bn.stR) {
                        rlo = fmaf(rlo, scR[2*e],   bbR[2*e]);
                        rhi = fmaf(rhi, scR[2*e+1], bbR[2*e+1]);
                    }
                    cp[e] = pack2(bflo(cp[e]) + rlo, bfhi(cp[e]) + rhi);
                }
            }
            *(int4*)(C + gb) = cv;
            if (ELR) {
                const int* cp = (const int*)&cv;
                float sl = 0.f, sr = 0.f;
                #pragma unroll
                for (int e = 0; e < 4; ++e) {
                    float lo = bflo(cp[e]), hi = bfhi(cp[e]);
                    sl = fmaf(lo, al[cb8 + 2*e], sl); sl = fmaf(hi, al[cb8 + 2*e + 1], sl);
                    sr = fmaf(lo, ar[cb8 + 2*e], sr); sr = fmaf(hi, ar[cb8 + 2*e + 1], sr);
                }
                elo[(size_t)grow * 16 + chunk] = sl;
                ero[(size_t)grow * 16 + chunk] = sr;
            }
            if (STATS) {
                const int* cp = (const int*)&cv;
                #pragma unroll
                for (int e = 0; e < 4; ++e) {
                    float lo = bflo(cp[e]), hi = bfhi(cp[e]);
                    sS[2*e]   += lo; sQ[2*e]   += lo * lo;
                    sS[2*e+1] += hi; sQ[2*e+1] += hi * hi;
                }
            }
        }
    }
    if (STATS) {
        __syncthreads();
        float* fs = (float*)Bs;   // 2048 sums + 2048 sq = 16 KB
        #pragma unroll
        for (int e = 0; e < 8; ++e) {
            fs[rgrp * 128 + cb8 + e]        = sS[e];
            fs[2048 + rgrp * 128 + cb8 + e] = sQ[e];
        }
        __syncthreads();
        if (t < 128) {
            float a = 0.f;
            #pragma unroll
            for (int g = 0; g < 16; ++g) a += fs[g * 128 + t];
            atomicAdd(&statsOut[t], a);
        } else {
            int c = t - 128;
            float a = 0.f;
            #pragma unroll
            for (int g = 0; g < 16; ++g) a += fs[2048 + g * 128 + c];
            atomicAdd(&statsOut[128 + c], a);
        }
    }
}

// ---------------- CSR build ----------------
__global__ void count_k(const int* __restrict__ dst, int* __restrict__ cnt, int E) {
    int e = blockIdx.x * 256 + threadIdx.x;
    if (e < E) atomicAdd(&cnt[dst[e]], 1);
}

__global__ __launch_bounds__(256) void scan_part_k(const int* __restrict__ cnt,
                                                   int* __restrict__ bsum, int Nn) {
    __shared__ int red[256];
    int base = blockIdx.x * 1024;
    int s = 0;
    for (int i = threadIdx.x; i < 1024; i += 256) {
        int g = base + i;
        if (g < Nn) s += cnt[g];
    }
    red[threadIdx.x] = s; __syncthreads();
    for (int off = 128; off; off >>= 1) {
        if ((int)threadIdx.x < off) red[threadIdx.x] += red[threadIdx.x + off];
        __syncthreads();
    }
    if (threadIdx.x == 0) bsum[blockIdx.x] = red[0];
}

__global__ __launch_bounds__(256) void scan_top_k(int* __restrict__ bsum, int nb) {
    __shared__ int buf[256];
    int v = ((int)threadIdx.x < nb) ? bsum[threadIdx.x] : 0;
    buf[threadIdx.x] = v; __syncthreads();
    for (int off = 1; off < 256; off <<= 1) {
        int tv = ((int)threadIdx.x >= off) ? buf[threadIdx.x - off] : 0;
        __syncthreads();
        buf[threadIdx.x] += tv;
        __syncthreads();
    }
    if ((int)threadIdx.x < nb) bsum[threadIdx.x] = buf[threadIdx.x] - v;
}

__global__ __launch_bounds__(256) void scan_fin_k(const int* __restrict__ cnt,
    const int* __restrict__ bsum, int* __restrict__ rowptr, int* __restrict__ wpos, int Nn)
{
    __shared__ int tsum[256];
    int base = blockIdx.x * 1024;
    int g0 = base + (int)threadIdx.x * 4;
    int v[4]; int s = 0;
    #pragma unroll
    for (int j = 0; j < 4; ++j) {
        int g = g0 + j;
        v[j] = (g < Nn) ? cnt[g] : 0;
        s += v[j];
    }
    tsum[threadIdx.x] = s; __syncthreads();
    for (int off = 1; off < 256; off <<= 1) {
        int tv = ((int)threadIdx.x >= off) ? tsum[threadIdx.x - off] : 0;
        __syncthreads();
        tsum[threadIdx.x] += tv;
        __syncthreads();
    }
    int run = bsum[blockIdx.x] + tsum[threadIdx.x] - s;
    #pragma unroll
    for (int j = 0; j < 4; ++j) {
        int g = g0 + j;
        if (g < Nn) { wpos[g] = run; rowptr[g + 1] = run + v[j]; }
        run += v[j];
    }
    if (blockIdx.x == 0 && threadIdx.x == 0) rowptr[0] = 0;
}

__global__ void scatter_k(const int* __restrict__ src, const int* __restrict__ dst,
                          int* __restrict__ wpos, int* __restrict__ esrc, int E) {
    int e = blockIdx.x * 256 + threadIdx.x;
    if (e < E) {
        int p = atomicAdd(&wpos[dst[e]], 1);
        esrc[p] = src[e];
    }
}

// ---------------- GAT aggregate (h-BN fused), online softmax, unroll x4 ----------------
__global__ __launch_bounds__(256) void gat_k(
    const short* __restrict__ h, const short* __restrict__ z,
    const float* __restrict__ el, const float* __restrict__ er,
    const int* __restrict__ rowptr, const int* __restrict__ esrc,
    const float* __restrict__ gbias, short* __restrict__ t1, int Nn,
    const float* __restrict__ hstats, const float* __restrict__ hg,
    const float* __restrict__ hb, float invN)
{
    int gw = (blockIdx.x * 256 + threadIdx.x) >> 6;
    if (gw >= Nn) return;
    int lane = threadIdx.x & 63;
    int c = lane * 2;
    int head = lane >> 2;
    float ern = er[gw*16 + head];
    int beg = rowptr[gw], end = rowptr[gw+1];
    float m = -3.0e38f, den = 0.f, a0 = 0.f, a1 = 0.f;
    int i = beg;
    for (; i + 3 < end; i += 4) {
        int s0 = esrc[i], s1 = esrc[i+1], s2 = esrc[i+2], s3 = esrc[i+3];
        float e0 = el[s0*16 + head] + ern;
        float e1 = el[s1*16 + head] + ern;
        float e2 = el[s2*16 + head] + ern;
        float e3 = el[s3*16 + head] + ern;
        int zz0 = *(const int*)(z + (size_t)s0*128 + c);
        int zz1 = *(const int*)(z + (size_t)s1*128 + c);
        int zz2 = *(const int*)(z + (size_t)s2*128 + c);
        int zz3 = *(const int*)(z + (size_t)s3*128 + c);
        e0 = (e0 > 0.f) ? e0 : 0.2f * e0;
        e1 = (e1 > 0.f) ? e1 : 0.2f * e1;
        e2 = (e2 > 0.f) ? e2 : 0.2f * e2;
        e3 = (e3 > 0.f) ? e3 : 0.2f * e3;
        float nm = fmaxf(fmaxf(fmaxf(e0, e1), fmaxf(e2, e3)), m);
        float sc = __expf(m - nm);
        float w0 = __expf(e0 - nm), w1 = __expf(e1 - nm);
        float w2 = __expf(e2 - nm), w3 = __expf(e3 - nm);
        den = fmaf(den, sc, (w0 + w1) + (w2 + w3));
        a0 = fmaf(a0, sc, fmaf(w0, bflo(zz0), fmaf(w1, bflo(zz1), fmaf(w2, bflo(zz2), w3 * bflo(zz3)))));
        a1 = fmaf(a1, sc, fmaf(w0, bfhi(zz0), fmaf(w1, bfhi(zz1), fmaf(w2, bfhi(zz2), w3 * bfhi(zz3)))));
        m = nm;
    }
    for (; i + 1 < end; i += 2) {
        int s0 = esrc[i], s1 = esrc[i+1];
        float e0 = el[s0*16 + head] + ern;
        float e1 = el[s1*16 + head] + ern;
        int zz0 = *(const int*)(z + (size_t)s0*128 + c);
        int zz1 = *(const int*)(z + (size_t)s1*128 + c);
        e0 = (e0 > 0.f) ? e0 : 0.2f * e0;
        e1 = (e1 > 0.f) ? e1 : 0.2f * e1;
        float nm = fmaxf(m, fmaxf(e0, e1));
        float sc = __expf(m - nm);
        float w0 = __expf(e0 - nm);
        float w1 = __expf(e1 - nm);
        den = fmaf(den, sc, w0 + w1);
        a0  = fmaf(a0, sc, fmaf(w0, bflo(zz0), w1 * bflo(zz1)));
        a1  = fmaf(a1, sc, fmaf(w0, bfhi(zz0), w1 * bfhi(zz1)));
        m = nm;
    }
    if (i < end) {
        int s0 = esrc[i];
        float e0 = el[s0*16 + head] + ern;
        int zz0 = *(const int*)(z + (size_t)s0*128 + c);
        e0 = (e0 > 0.f) ? e0 : 0.2f * e0;
        float nm = fmaxf(m, e0);
        float sc = __expf(m - nm);
        float w0 = __expf(e0 - nm);
        den = fmaf(den, sc, w0);
        a0  = fmaf(a0, sc, w0 * bflo(zz0));
        a1  = fmaf(a1, sc, w0 * bfhi(zz0));
    }
    float inv = 1.f / den;
    size_t o = (size_t)gw*64 + lane;
    int hv = ((const int*)h)[o];
    float h0 = bflo(hv), h1 = bfhi(hv);
    if (hstats) {
        float mu0 = hstats[c] * invN;
        float v0  = hstats[128+c] * invN - mu0*mu0;
        float s0  = rsqrtf(v0 + 1e-5f) * hg[c];
        h0 = fmaf(h0 - mu0, s0, hb[c]);
        float mu1 = hstats[c+1] * invN;
        float v1  = hstats[128+c+1] * invN - mu1*mu1;
        float s1  = rsqrtf(v1 + 1e-5f) * hg[c+1];
        h1 = fmaf(h1 - mu1, s1, hb[c+1]);
    }
    float r0 = h0 + a0*inv + gbias[c];
    float r1 = h1 + a1*inv + gbias[c+1];
    ((int*)t1)[o] = pack2(r0, r1);
}

// ---------------- BatchNorm stats (for t1 after GAT) ----------------
__global__ __launch_bounds__(256) void bn_stats_k(const short* __restrict__ xin,
    float* __restrict__ stats, int Nn)
{
    __shared__ float s0s[256], s1s[256], q0s[256], q1s[256];
    int pair = threadIdx.x & 63;
    int slot = threadIdx.x >> 6;
    float s0 = 0.f, s1 = 0.f, q0 = 0.f, q1 = 0.f;
    for (int r = blockIdx.x*4 + slot; r < Nn; r += gridDim.x*4) {
        int v = *(const int*)(xin + (size_t)r*128 + pair*2);
        float a = bflo(v), b = bfhi(v);
        s0 += a; s1 += b;
        q0 = fmaf(a, a, q0); q1 = fmaf(b, b, q1);
    }
    s0s[threadIdx.x] = s0; s1s[threadIdx.x] = s1;
    q0s[threadIdx.x] = q0; q1s[threadIdx.x] = q1;
    __syncthreads();
    if (slot == 0) {
        #pragma unroll
        for (int j = 1; j < 4; ++j) {
            s0 += s0s[pair + j*64]; s1 += s1s[pair + j*64];
            q0 += q0s[pair + j*64]; q1 += q1s[pair + j*64];
        }
        atomicAdd(&stats[pair*2],       s0);
        atomicAdd(&stats[pair*2+1],     s1);
        atomicAdd(&stats[128+pair*2],   q0);
        atomicAdd(&stats[128+pair*2+1], q1);
    }
}

// ---------------- decoder output ----------------
__global__ __launch_bounds__(256) void dec_out_k(const short* __restrict__ udec,
    const float* __restrict__ W2, const float* __restrict__ b2,
    float* __restrict__ out, int Nn)
{
    int gw = (blockIdx.x * 256 + threadIdx.x) >> 6;
    if (gw >= Nn) return;
    int lane = threadIdx.x & 63;
    int v = ((const int*)(udec + (size_t)gw * 128))[lane];
    float p = bflo(v) * W2[lane*2] + bfhi(v) * W2[lane*2 + 1];
    #pragma unroll
    for (int off = 32; off > 0; off >>= 1) p += __shfl_down(p, off);
    if (lane == 0) out[gw] = p + b2[0];
}

extern "C" void kernel_launch(void* const* d_in, const int* in_sizes, int n_in,
                              void* d_out, int out_size, void* d_ws, size_t ws_size,
                              hipStream_t stream)
{
    const float* x      = (const float*)d_in[0];
    const int*   src    = (const int*)  d_in[1];
    const int*   dst    = (const int*)  d_in[2];
    const float* emb_W1 = (const float*)d_in[3];
    const float* emb_b1 = (const float*)d_in[4];
    const float* emb_W2 = (const float*)d_in[5];
    const float* emb_b2 = (const float*)d_in[6];
    const float* emb_Ws = (const float*)d_in[7];
    const float* emb_bs = (const float*)d_in[8];
    const float* gat_W  = (const float*)d_in[9];
    const float* gat_al = (const float*)d_in[10];
    const float* gat_ar = (const float*)d_in[11];
    const float* gat_b  = (const float*)d_in[12];
    const float* bn1_g  = (const float*)d_in[13];
    const float* bn1_b  = (const float*)d_in[14];
    const float* ff_W1  = (const float*)d_in[15];
    const float* ff_b1  = (const float*)d_in[16];
    const float* ff_W2  = (const float*)d_in[17];
    const float* ff_b2  = (const float*)d_in[18];
    const float* bn2_g  = (const float*)d_in[19];
    const float* bn2_b  = (const float*)d_in[20];
    const float* dec_W1 = (const float*)d_in[21];
    const float* dec_b1 = (const float*)d_in[22];
    const float* dec_W2 = (const float*)d_in[23];
    const float* dec_b2 = (const float*)d_in[24];
    float* out = (float*)d_out;
    (void)n_in; (void)out_size;

    const int N = in_sizes[0] / 2;
    const int E = in_sizes[1];
    const float invN = 1.f / (float)N;

    // ---- workspace ----
    char* p = (char*)d_ws;
    size_t used = 0;
    auto carve = [&](size_t bytes) {
        char* r = p; size_t a = (bytes + 255) & ~(size_t)255;
        p += a; used += a; return r;
    };
    const size_t nbH = (size_t)N * 128 * 2;
    short* xs[5];                                  // xs[0]=embed out; xs[l+1]=t2_l (raw, pre-BN2)
    for (int i = 0; i < 5; ++i) xs[i] = (short*)carve(nbH);
    short* t1   = (short*)carve(nbH);              // GAT out (raw, pre-BN1)
    char*  big  = (char*)carve(2 * nbH);           // u / (z | el | er) / ffh / udec
    int*   cnt    = (int*)carve((size_t)N * 4);
    float* stats8 = (float*)carve(8 * 256 * 4);    // adjacent to cnt: zeroed together
    int*   rowptr = (int*)carve((size_t)(N + 1) * 4);
    int*   wpos   = (int*)carve((size_t)N * 4);
    int*   esrc   = (int*)carve((size_t)E * 4);
    int*   bsum   = (int*)carve(256 * 4);
    short* emb_W2t = (short*)carve((size_t)128 * 128 * 2);
    short* gat_Wt  = (short*)carve((size_t)4 * 128 * 128 * 2);
    short* ff_W1t  = (short*)carve((size_t)4 * 128 * 256 * 2);
    short* ff_W2t  = (short*)carve((size_t)4 * 256 * 128 * 2);
    short* dec_W1t = (short*)carve((size_t)640 * 128 * 2);
    if (used > ws_size) return;

    short* u    = (short*)big;
    short* z    = (short*)big;
    float* el   = (float*)(big + nbH);
    float* er   = el + (size_t)N * 16;
    short* ffh  = (short*)big;
    short* udec = (short*)big;

    dim3 b256(256);
    int ecb  = (E + 255) / 256;
    int nel2 = (N * 64 + 255) / 256;
    int gx   = (N + 127) / 128;
    int nwv  = (N + 3) / 4;
    int nb   = (N + 1023) / 1024;

    BN5 bn0;
    for (int i = 0; i < 5; ++i) { bn0.st[i] = nullptr; bn0.g[i] = nullptr; bn0.b[i] = nullptr; }
    bn0.stR = nullptr; bn0.gR = nullptr; bn0.bR = nullptr; bn0.invN = invN;

    // ---- weight convert + transpose ----
    wconv_k<<<dim3(64, 1), b256, 0, stream>>>(emb_W2, emb_W2t, 128, 128);
    wconv_k<<<dim3(64, 4), b256, 0, stream>>>(gat_W,  gat_Wt,  128, 128);
    wconv_k<<<dim3(128, 4), b256, 0, stream>>>(ff_W1, ff_W1t,  128, 256);
    wconv_k<<<dim3(128, 4), b256, 0, stream>>>(ff_W2, ff_W2t,  256, 128);
    wconv_k<<<dim3(320, 1), b256, 0, stream>>>(dec_W1, dec_W1t, 640, 128);

    // ---- zero cnt + 8 BN stats buffers ----
    {
        int ztot = (int)(((char*)(stats8 + 8*256) - (char*)cnt) / 4);
        zero_i32_k<<<(ztot + 255) / 256, b256, 0, stream>>>(cnt, ztot);
    }

    // ---- CSR build ----
    count_k<<<ecb, b256, 0, stream>>>(dst, cnt, E);
    scan_part_k<<<nb, b256, 0, stream>>>(cnt, bsum, N);
    scan_top_k<<<1, b256, 0, stream>>>(bsum, nb);
    scan_fin_k<<<nb, b256, 0, stream>>>(cnt, bsum, rowptr, wpos, N);
    scatter_k<<<ecb, b256, 0, stream>>>(src, dst, wpos, esrc, E);

    // ---- embed: xs0 = relu(x@W1+b1)@W2 + b2 + (x@Ws+bs) ----
    embed_k<<<nel2, b256, 0, stream>>>(x, emb_W1, emb_b1, emb_Ws, emb_bs, (int*)u, (int*)xs[0], N);
    gemm2_k<1,0,1,0,0><<<dim3(gx,1), b256, 0, stream>>>(u,u,u,u,u, 128, emb_W2t, 128,
        emb_b2, xs[0], nullptr, N, 128, bn0, nullptr, nullptr, nullptr, nullptr, nullptr);

    for (int l = 0; l < 4; ++l) {
        float* st1 = stats8 + (size_t)(l*2)   * 256;   // stats of t1 (GAT out)
        float* st2 = stats8 + (size_t)(l*2+1) * 256;   // stats of t2 (FF out) — filled by FF2 epilogue
        short* hl = xs[l];                             // raw; BN2 of prev layer fused on read
        const float* hst = (l == 0) ? nullptr : stats8 + (size_t)((l-1)*2+1) * 256;
        const float* hgp = (l == 0) ? nullptr : bn2_g + (l-1)*128;
        const float* hbp = (l == 0) ? nullptr : bn2_b + (l-1)*128;

        // z = bn2(xs[l]) @ gatW[l]  (+ fused el/er)
        BN5 bz = bn0; bz.st[0] = hst; bz.g[0] = hgp; bz.b[0] = hbp;
        gemm2_k<1,0,0,1,0><<<dim3(gx,1), b256, 0, stream>>>(hl,hl,hl,hl,hl, 128,
            gat_Wt + (size_t)l*128*128, 128, nullptr, z, nullptr, N, 128, bz,
            gat_al + l*128, gat_ar + l*128, el, er, nullptr);
        gat_k<<<nwv, b256, 0, stream>>>(hl, z, el, er, rowptr, esrc, gat_b + l*128, t1, N,
                                        hst, hgp, hbp, invN);
        bn_stats_k<<<400, b256, 0, stream>>>(t1, st1, N);
        // FF1: ffh = relu(bn1(t1)@W1+b1)
        BN5 bf1 = bn0; bf1.st[0] = st1; bf1.g[0] = bn1_g + l*128; bf1.b[0] = bn1_b + l*128;
        gemm2_k<1,1,0,0,0><<<dim3(gx,2), b256, 0, stream>>>(t1,t1,t1,t1,t1, 128,
            ff_W1t + (size_t)l*128*256, 128, ff_b1 + l*256, ffh, nullptr, N, 256, bf1,
            nullptr, nullptr, nullptr, nullptr, nullptr);
        // FF2: xs[l+1] = bn1(t1) + ffh@W2 + b2   (+ fused stats -> st2)
        BN5 bf2 = bn0; bf2.stR = st1; bf2.gR = bn1_g + l*128; bf2.bR = bn1_b + l*128;
        gemm2_k<2,0,1,0,1><<<dim3(gx,1), b256, 0, stream>>>(ffh, ffh + 128, ffh, ffh, ffh, 256,
            ff_W2t + (size_t)l*256*128, 256, ff_b2 + l*128, xs[l+1], t1, N, 128, bf2,
            nullptr, nullptr, nullptr, nullptr, st2);
    }

    // ---- decoder: udec = relu(concat(xs0, bn2(t2_l)) @ dec_W1 + b1) ----
    BN5 bd = bn0;
    for (int k = 1; k < 5; ++k) {
        bd.st[k] = stats8 + (size_t)((k-1)*2+1) * 256;
        bd.g[k]  = bn2_g + (k-1)*128;
        bd.b[k]  = bn2_b + (k-1)*128;
    }
    gemm2_k<5,1,0,0,0><<<dim3(gx,1), b256, 0, stream>>>(xs[0], xs[1], xs[2], xs[3], xs[4], 128,
        dec_W1t, 640, dec_b1, udec, nullptr, N, 128, bd,
        nullptr, nullptr, nullptr, nullptr, nullptr);
    dec_out_k<<<nwv, b256, 0, stream>>>(udec, dec_W2, dec_b2, out, N);
}

// Round 11
// 1061.814 us; speedup vs baseline: 1.5629x; 1.0797x over previous
//
#include <hip/hip_runtime.h>
#include <math.h>

typedef __attribute__((ext_vector_type(8))) short bf16x8;
typedef __attribute__((ext_vector_type(4))) float f32x4;

struct BN5 {
    const float* st[5];
    const float* g[5];
    const float* b[5];
    const float* stR;
    const float* gR;
    const float* bR;
    float invN;
};

static __device__ __forceinline__ short f2bf(float f) {
    unsigned u = __float_as_uint(f);
    unsigned r = (u + 0x7fffu + ((u >> 16) & 1u)) >> 16;
    return (short)r;
}
static __device__ __forceinline__ float bf2f(short s) {
    return __uint_as_float(((unsigned)(unsigned short)s) << 16);
}
static __device__ __forceinline__ float bflo(int v) { return bf2f((short)(v & 0xffff)); }
static __device__ __forceinline__ float bfhi(int v) { return bf2f((short)(((unsigned)v) >> 16)); }
static __device__ __forceinline__ int pack2(float a, float b) {
    return (int)(((unsigned)(unsigned short)f2bf(b) << 16) | (unsigned)(unsigned short)f2bf(a));
}

// ---------------- zero fill ----------------
__global__ void zero_i32_k(int* __restrict__ p, int n) {
    int i = blockIdx.x * 256 + threadIdx.x;
    if (i < n) p[i] = 0;
}

// ---------------- weight convert+transpose ----------------
__global__ __launch_bounds__(256) void wconv_k(const float* __restrict__ W, short* __restrict__ Wt,
                                               int K, int Nc) {
    int slice = blockIdx.y;
    const float* src = W + (size_t)slice * K * Nc;
    short* dst = Wt + (size_t)slice * K * Nc;
    int idx = blockIdx.x * 256 + threadIdx.x;
    if (idx >= K * Nc) return;
    int k = idx / Nc, n = idx - k * Nc;
    dst[(size_t)n * K + k] = f2bf(src[idx]);
}

// ---------------- embed ----------------
__global__ __launch_bounds__(256) void embed_k(
    const float* __restrict__ x, const float* __restrict__ W1, const float* __restrict__ b1,
    const float* __restrict__ Ws, const float* __restrict__ bs,
    int* __restrict__ u2, int* __restrict__ h2, int Nn)
{
    int idx = blockIdx.x * 256 + threadIdx.x;
    if (idx >= Nn * 64) return;
    int n = idx >> 6, c = (idx & 63) * 2;
    float x0 = x[2*n], x1 = x[2*n+1];
    float u0 = fmaxf(fmaf(x1, W1[128+c],   fmaf(x0, W1[c],   b1[c])),   0.f);
    float u1 = fmaxf(fmaf(x1, W1[128+c+1], fmaf(x0, W1[c+1], b1[c+1])), 0.f);
    float h0 = fmaf(x1, Ws[128+c],   fmaf(x0, Ws[c],   bs[c]));
    float h1 = fmaf(x1, Ws[128+c+1], fmaf(x0, Ws[c+1], bs[c+1]));
    u2[idx] = pack2(u0, u1);
    h2[idx] = pack2(h0, h1);
}

// ------- bf16 MFMA GEMM (R10 structure: B in LDS, A prefetch, BN fusion) -------
template<int NK, int RELU, int BETA, int ELR>
__global__ __launch_bounds__(256) void gemm2_k(
    const short* __restrict__ A0, const short* __restrict__ A1,
    const short* __restrict__ A2, const short* __restrict__ A3,
    const short* __restrict__ A4, int Astr,
    const short* __restrict__ Wt, int ldWt,
    const float* __restrict__ bias, short* __restrict__ C, const short* __restrict__ Rres,
    int Nrows, int ldC, BN5 bn,
    const float* __restrict__ al, const float* __restrict__ ar,
    float* __restrict__ elo, float* __restrict__ ero)
{
    __shared__ short Bs[128][136];
    const int row0 = blockIdx.x * 128;
    const int col0 = blockIdx.y * 128;
    const int t = threadIdx.x;
    const int w = t >> 6, lane = t & 63, q = lane >> 4, m = lane & 15;

    f32x4 acc[2][8];
    #pragma unroll
    for (int rb = 0; rb < 2; ++rb)
        #pragma unroll
        for (int cb = 0; cb < 8; ++cb)
            acc[rb][cb] = (f32x4){0.f, 0.f, 0.f, 0.f};

    const short* Asrc[5] = {A0, A1, A2, A3, A4};
    int rr0 = row0 + w*32 + m;      if (rr0 > Nrows - 1) rr0 = Nrows - 1;
    int rr1 = row0 + w*32 + 16 + m; if (rr1 > Nrows - 1) rr1 = Nrows - 1;

    #pragma unroll
    for (int kh = 0; kh < NK; ++kh) {
        if (kh) __syncthreads();
        #pragma unroll
        for (int it = 0; it < 8; ++it) {
            int ci = t + it * 256;
            int r = ci >> 4, j = (ci & 15) * 8;
            *(int4*)&Bs[r][j] = *(const int4*)(Wt + (size_t)(col0 + r) * ldWt + kh * 128 + j);
        }
        const short* pa0 = Asrc[kh] + (size_t)rr0 * Astr + q * 8;
        const short* pa1 = Asrc[kh] + (size_t)rr1 * Astr + q * 8;
        bf16x8 af0[4], af1[4];
        #pragma unroll
        for (int ks = 0; ks < 4; ++ks) {
            af0[ks] = *(const bf16x8*)(pa0 + ks * 32);
            af1[ks] = *(const bf16x8*)(pa1 + ks * 32);
        }
        if (bn.st[kh]) {
            const float* st = bn.st[kh];
            const float* gg = bn.g[kh];
            const float* bb = bn.b[kh];
            #pragma unroll
            for (int ks = 0; ks < 4; ++ks) {
                #pragma unroll
                for (int e = 0; e < 8; ++e) {
                    int c = ks * 32 + q * 8 + e;
                    float mu = st[c] * bn.invN;
                    float var = st[128 + c] * bn.invN - mu * mu;
                    float sc = rsqrtf(var + 1e-5f) * gg[c];
                    float bc = bb[c] - mu * sc;
                    af0[ks][e] = f2bf(fmaf(bf2f(af0[ks][e]), sc, bc));
                    af1[ks][e] = f2bf(fmaf(bf2f(af1[ks][e]), sc, bc));
                }
            }
        }
        __syncthreads();
        #pragma unroll
        for (int ks = 0; ks < 4; ++ks) {
            bf16x8 bfr[8];
            #pragma unroll
            for (int cb = 0; cb < 8; ++cb)
                bfr[cb] = *(const bf16x8*)&Bs[cb * 16 + m][ks * 32 + q * 8];
            #pragma unroll
            for (int cb = 0; cb < 8; ++cb) {
                acc[0][cb] = __builtin_amdgcn_mfma_f32_16x16x32_bf16(af0[ks], bfr[cb], acc[0][cb], 0, 0, 0);
                acc[1][cb] = __builtin_amdgcn_mfma_f32_16x16x32_bf16(af1[ks], bfr[cb], acc[1][cb], 0, 0, 0);
            }
        }
    }

    __syncthreads();
    short* Cs = (short*)Bs;
    #pragma unroll
    for (int rb = 0; rb < 2; ++rb) {
        #pragma unroll
        for (int r = 0; r < 4; ++r) {
            int lrow = w * 32 + rb * 16 + q * 4 + r;
            #pragma unroll
            for (int cb = 0; cb < 8; ++cb) {
                float v = acc[rb][cb][r];
                if (bias) v += bias[col0 + cb * 16 + m];
                if (RELU) v = fmaxf(v, 0.f);
                Cs[lrow * 132 + cb * 16 + m] = f2bf(v);
            }
        }
    }
    __syncthreads();
    const int chunk = t & 15, rgrp = t >> 4, cb8 = chunk * 8;
    const short* Rd = Rres ? Rres : C;
    #pragma unroll
    for (int j = 0; j < 8; ++j) {
        int r = rgrp + j * 16;
        int grow = row0 + r;
        if (grow < Nrows) {
            int2 u0 = *(const int2*)(Cs + r * 132 + cb8);
            int2 u1 = *(const int2*)(Cs + r * 132 + cb8 + 4);
            int4 cv = make_int4(u0.x, u0.y, u1.x, u1.y);
            size_t gb = (size_t)grow * ldC + col0 + cb8;
            if (BETA) {
                int4 rv = *(const int4*)(Rd + gb);
                int* cp = (int*)&cv; const int* rp = (const int*)&rv;
                #pragma unroll
                for (int e = 0; e < 4; ++e)
                    cp[e] = pack2(bflo(cp[e]) + bflo(rp[e]), bfhi(cp[e]) + bfhi(rp[e]));
            }
            *(int4*)(C + gb) = cv;
            if (ELR) {
                const int* cp = (const int*)&cv;
                float sl = 0.f, sr = 0.f;
                #pragma unroll
                for (int e = 0; e < 4; ++e) {
                    float lo = bflo(cp[e]), hi = bfhi(cp[e]);
                    sl = fmaf(lo, al[cb8 + 2*e], sl); sl = fmaf(hi, al[cb8 + 2*e + 1], sl);
                    sr = fmaf(lo, ar[cb8 + 2*e], sr); sr = fmaf(hi, ar[cb8 + 2*e + 1], sr);
                }
                elo[(size_t)grow * 16 + chunk] = sl;
                ero[(size_t)grow * 16 + chunk] = sr;
            }
        }
    }
}

// ------- fused FF block: xs = bn1(t1) + relu(bn1(t1)@W1+b1)@W2 + b2, + stats -------
// K-split over ffh columns: per 128-col half, ffh_half tile lives only in LDS.
__global__ __launch_bounds__(256) void ff_fused_k(
    const short* __restrict__ T1,
    const short* __restrict__ W1t,   // [256 cols][128 k]
    const short* __restrict__ W2t,   // [128 cols][256 k]
    const float* __restrict__ b1, const float* __restrict__ b2,
    const float* __restrict__ st1, const float* __restrict__ g1, const float* __restrict__ bb1,
    float invN, short* __restrict__ C, int Nrows, float* __restrict__ statsOut)
{
    __shared__ short Wbuf[128][136];
    __shared__ short Fbuf[128 * 132];
    const int row0 = blockIdx.x * 128;
    const int t = threadIdx.x;
    const int w = t >> 6, lane = t & 63, q = lane >> 4, m = lane & 15;

    f32x4 acc2[2][8];
    #pragma unroll
    for (int rb = 0; rb < 2; ++rb)
        #pragma unroll
        for (int cb = 0; cb < 8; ++cb)
            acc2[rb][cb] = (f32x4){0.f, 0.f, 0.f, 0.f};

    int rr0 = row0 + w*32 + m;      if (rr0 > Nrows - 1) rr0 = Nrows - 1;
    int rr1 = row0 + w*32 + 16 + m; if (rr1 > Nrows - 1) rr1 = Nrows - 1;

    // A fragments of bn1(t1), loaded once, reused for both halves
    bf16x8 af0[4], af1[4];
    {
        const short* pa0 = T1 + (size_t)rr0 * 128 + q * 8;
        const short* pa1 = T1 + (size_t)rr1 * 128 + q * 8;
        #pragma unroll
        for (int ks = 0; ks < 4; ++ks) {
            af0[ks] = *(const bf16x8*)(pa0 + ks * 32);
            af1[ks] = *(const bf16x8*)(pa1 + ks * 32);
        }
        #pragma unroll
        for (int ks = 0; ks < 4; ++ks) {
            #pragma unroll
            for (int e = 0; e < 8; ++e) {
                int c = ks * 32 + q * 8 + e;
                float mu = st1[c] * invN;
                float var = st1[128 + c] * invN - mu * mu;
                float sc = rsqrtf(var + 1e-5f) * g1[c];
                float bc = bb1[c] - mu * sc;
                af0[ks][e] = f2bf(fmaf(bf2f(af0[ks][e]), sc, bc));
                af1[ks][e] = f2bf(fmaf(bf2f(af1[ks][e]), sc, bc));
            }
        }
    }

    #pragma unroll
    for (int half = 0; half < 2; ++half) {
        if (half) __syncthreads();   // prior MFMA2 reads of Wbuf done
        // stage W1 half: cols half*128..+128, k 0..128
        #pragma unroll
        for (int it = 0; it < 8; ++it) {
            int ci = t + it * 256;
            int r = ci >> 4, j = (ci & 15) * 8;
            *(int4*)&Wbuf[r][j] = *(const int4*)(W1t + (size_t)(half * 128 + r) * 128 + j);
        }
        __syncthreads();
        // MFMA1: ffh_half = af x W1half
        f32x4 acc1[2][8];
        #pragma unroll
        for (int rb = 0; rb < 2; ++rb)
            #pragma unroll
            for (int cb = 0; cb < 8; ++cb)
                acc1[rb][cb] = (f32x4){0.f, 0.f, 0.f, 0.f};
        #pragma unroll
        for (int ks = 0; ks < 4; ++ks) {
            bf16x8 bfr[8];
            #pragma unroll
            for (int cb = 0; cb < 8; ++cb)
                bfr[cb] = *(const bf16x8*)&Wbuf[cb * 16 + m][ks * 32 + q * 8];
            #pragma unroll
            for (int cb = 0; cb < 8; ++cb) {
                acc1[0][cb] = __builtin_amdgcn_mfma_f32_16x16x32_bf16(af0[ks], bfr[cb], acc1[0][cb], 0, 0, 0);
                acc1[1][cb] = __builtin_amdgcn_mfma_f32_16x16x32_bf16(af1[ks], bfr[cb], acc1[1][cb], 0, 0, 0);
            }
        }
        // relu + bias, write ffh_half tile to Fbuf (C-layout -> row-major)
        #pragma unroll
        for (int rb = 0; rb < 2; ++rb) {
            #pragma unroll
            for (int r = 0; r < 4; ++r) {
                int lrow = w * 32 + rb * 16 + q * 4 + r;
                #pragma unroll
                for (int cb = 0; cb < 8; ++cb) {
                    float v = acc1[rb][cb][r] + b1[half * 128 + cb * 16 + m];
                    Fbuf[lrow * 132 + cb * 16 + m] = f2bf(fmaxf(v, 0.f));
                }
            }
        }
        __syncthreads();   // MFMA1 reads of Wbuf + Fbuf writes complete
        // stage W2 half: cols 0..128, k half*128..+128
        #pragma unroll
        for (int it = 0; it < 8; ++it) {
            int ci = t + it * 256;
            int r = ci >> 4, j = (ci & 15) * 8;
            *(int4*)&Wbuf[r][j] = *(const int4*)(W2t + (size_t)r * 256 + half * 128 + j);
        }
        __syncthreads();
        // MFMA2: acc2 += ffh_half x W2half  (A from Fbuf)
        const short* fa0 = Fbuf + (w * 32 + m) * 132 + q * 8;
        const short* fa1 = Fbuf + (w * 32 + 16 + m) * 132 + q * 8;
        #pragma unroll
        for (int ks = 0; ks < 4; ++ks) {
            bf16x8 ga0 = *(const bf16x8*)(fa0 + ks * 32);
            bf16x8 ga1 = *(const bf16x8*)(fa1 + ks * 32);
            bf16x8 bfr[8];
            #pragma unroll
            for (int cb = 0; cb < 8; ++cb)
                bfr[cb] = *(const bf16x8*)&Wbuf[cb * 16 + m][ks * 32 + q * 8];
            #pragma unroll
            for (int cb = 0; cb < 8; ++cb) {
                acc2[0][cb] = __builtin_amdgcn_mfma_f32_16x16x32_bf16(ga0, bfr[cb], acc2[0][cb], 0, 0, 0);
                acc2[1][cb] = __builtin_amdgcn_mfma_f32_16x16x32_bf16(ga1, bfr[cb], acc2[1][cb], 0, 0, 0);
            }
        }
    }

    // ---- epilogue: + b2 + bn1(t1) residual, store, fused stats ----
    __syncthreads();
    #pragma unroll
    for (int rb = 0; rb < 2; ++rb) {
        #pragma unroll
        for (int r = 0; r < 4; ++r) {
            int lrow = w * 32 + rb * 16 + q * 4 + r;
            #pragma unroll
            for (int cb = 0; cb < 8; ++cb) {
                float v = acc2[rb][cb][r] + b2[cb * 16 + m];
                Fbuf[lrow * 132 + cb * 16 + m] = f2bf(v);
            }
        }
    }
    __syncthreads();
    const int chunk = t & 15, rgrp = t >> 4, cb8 = chunk * 8;
    float scR[8], bbR[8];
    #pragma unroll
    for (int e = 0; e < 8; ++e) {
        int c = cb8 + e;
        float mu = st1[c] * invN;
        float var = st1[128 + c] * invN - mu * mu;
        float sc = rsqrtf(var + 1e-5f) * g1[c];
        scR[e] = sc; bbR[e] = bb1[c] - mu * sc;
    }
    float sS[8], sQ[8];
    #pragma unroll
    for (int e = 0; e < 8; ++e) { sS[e] = 0.f; sQ[e] = 0.f; }
    #pragma unroll
    for (int j = 0; j < 8; ++j) {
        int r = rgrp + j * 16;
        int grow = row0 + r;
        if (grow < Nrows) {
            int2 u0 = *(const int2*)(Fbuf + r * 132 + cb8);
            int2 u1 = *(const int2*)(Fbuf + r * 132 + cb8 + 4);
            int4 cv = make_int4(u0.x, u0.y, u1.x, u1.y);
            size_t gb = (size_t)grow * 128 + cb8;
            int4 rv = *(const int4*)(T1 + gb);
            int* cp = (int*)&cv; const int* rp = (const int*)&rv;
            #pragma unroll
            for (int e = 0; e < 4; ++e) {
                float rlo = fmaf(bflo(rp[e]), scR[2*e],   bbR[2*e]);
                float rhi = fmaf(bfhi(rp[e]), scR[2*e+1], bbR[2*e+1]);
                float lo = bflo(cp[e]) + rlo;
                float hi = bfhi(cp[e]) + rhi;
                cp[e] = pack2(lo, hi);
                lo = bflo(cp[e]); hi = bfhi(cp[e]);
                sS[2*e]   += lo; sQ[2*e]   += lo * lo;
                sS[2*e+1] += hi; sQ[2*e+1] += hi * hi;
            }
            *(int4*)(C + gb) = cv;
        }
    }
    __syncthreads();
    float* fs = (float*)Wbuf;
    #pragma unroll
    for (int e = 0; e < 8; ++e) {
        fs[rgrp * 128 + cb8 + e]        = sS[e];
        fs[2048 + rgrp * 128 + cb8 + e] = sQ[e];
    }
    __syncthreads();
    if (t < 128) {
        float a = 0.f;
        #pragma unroll
        for (int g = 0; g < 16; ++g) a += fs[g * 128 + t];
        atomicAdd(&statsOut[t], a);
    } else {
        int c = t - 128;
        float a = 0.f;
        #pragma unroll
        for (int g = 0; g < 16; ++g) a += fs[2048 + g * 128 + c];
        atomicAdd(&statsOut[128 + c], a);
    }
}

// ---------------- CSR build ----------------
__global__ void count_k(const int* __restrict__ dst, int* __restrict__ cnt, int E) {
    int e = blockIdx.x * 256 + threadIdx.x;
    if (e < E) atomicAdd(&cnt[dst[e]], 1);
}

__global__ __launch_bounds__(256) void scan_part_k(const int* __restrict__ cnt,
                                                   int* __restrict__ bsum, int Nn) {
    __shared__ int red[256];
    int base = blockIdx.x * 1024;
    int s = 0;
    for (int i = threadIdx.x; i < 1024; i += 256) {
        int g = base + i;
        if (g < Nn) s += cnt[g];
    }
    red[threadIdx.x] = s; __syncthreads();
    for (int off = 128; off; off >>= 1) {
        if ((int)threadIdx.x < off) red[threadIdx.x] += red[threadIdx.x + off];
        __syncthreads();
    }
    if (threadIdx.x == 0) bsum[blockIdx.x] = red[0];
}

__global__ __launch_bounds__(256) void scan_top_k(int* __restrict__ bsum, int nb) {
    __shared__ int buf[256];
    int v = ((int)threadIdx.x < nb) ? bsum[threadIdx.x] : 0;
    buf[threadIdx.x] = v; __syncthreads();
    for (int off = 1; off < 256; off <<= 1) {
        int tv = ((int)threadIdx.x >= off) ? buf[threadIdx.x - off] : 0;
        __syncthreads();
        buf[threadIdx.x] += tv;
        __syncthreads();
    }
    if ((int)threadIdx.x < nb) bsum[threadIdx.x] = buf[threadIdx.x] - v;
}

__global__ __launch_bounds__(256) void scan_fin_k(const int* __restrict__ cnt,
    const int* __restrict__ bsum, int* __restrict__ rowptr, int* __restrict__ wpos, int Nn)
{
    __shared__ int tsum[256];
    int base = blockIdx.x * 1024;
    int g0 = base + (int)threadIdx.x * 4;
    int v[4]; int s = 0;
    #pragma unroll
    for (int j = 0; j < 4; ++j) {
        int g = g0 + j;
        v[j] = (g < Nn) ? cnt[g] : 0;
        s += v[j];
    }
    tsum[threadIdx.x] = s; __syncthreads();
    for (int off = 1; off < 256; off <<= 1) {
        int tv = ((int)threadIdx.x >= off) ? tsum[threadIdx.x - off] : 0;
        __syncthreads();
        tsum[threadIdx.x] += tv;
        __syncthreads();
    }
    int run = bsum[blockIdx.x] + tsum[threadIdx.x] - s;
    #pragma unroll
    for (int j = 0; j < 4; ++j) {
        int g = g0 + j;
        if (g < Nn) { wpos[g] = run; rowptr[g + 1] = run + v[j]; }
        run += v[j];
    }
    if (blockIdx.x == 0 && threadIdx.x == 0) rowptr[0] = 0;
}

__global__ void scatter_k(const int* __restrict__ src, const int* __restrict__ dst,
                          int* __restrict__ wpos, int* __restrict__ esrc, int E) {
    int e = blockIdx.x * 256 + threadIdx.x;
    if (e < E) {
        int p = atomicAdd(&wpos[dst[e]], 1);
        esrc[p] = src[e];
    }
}

// ---------------- GAT aggregate (h-BN fused), online softmax, unroll x4 ----------------
__global__ __launch_bounds__(256) void gat_k(
    const short* __restrict__ h, const short* __restrict__ z,
    const float* __restrict__ el, const float* __restrict__ er,
    const int* __restrict__ rowptr, const int* __restrict__ esrc,
    const float* __restrict__ gbias, short* __restrict__ t1, int Nn,
    const float* __restrict__ hstats, const float* __restrict__ hg,
    const float* __restrict__ hb, float invN)
{
    int gw = (blockIdx.x * 256 + threadIdx.x) >> 6;
    if (gw >= Nn) return;
    int lane = threadIdx.x & 63;
    int c = lane * 2;
    int head = lane >> 2;
    float ern = er[gw*16 + head];
    int beg = rowptr[gw], end = rowptr[gw+1];
    float m = -3.0e38f, den = 0.f, a0 = 0.f, a1 = 0.f;
    int i = beg;
    for (; i + 3 < end; i += 4) {
        int s0 = esrc[i], s1 = esrc[i+1], s2 = esrc[i+2], s3 = esrc[i+3];
        float e0 = el[s0*16 + head] + ern;
        float e1 = el[s1*16 + head] + ern;
        float e2 = el[s2*16 + head] + ern;
        float e3 = el[s3*16 + head] + ern;
        int zz0 = *(const int*)(z + (size_t)s0*128 + c);
        int zz1 = *(const int*)(z + (size_t)s1*128 + c);
        int zz2 = *(const int*)(z + (size_t)s2*128 + c);
        int zz3 = *(const int*)(z + (size_t)s3*128 + c);
        e0 = (e0 > 0.f) ? e0 : 0.2f * e0;
        e1 = (e1 > 0.f) ? e1 : 0.2f * e1;
        e2 = (e2 > 0.f) ? e2 : 0.2f * e2;
        e3 = (e3 > 0.f) ? e3 : 0.2f * e3;
        float nm = fmaxf(fmaxf(fmaxf(e0, e1), fmaxf(e2, e3)), m);
        float sc = __expf(m - nm);
        float w0 = __expf(e0 - nm), w1 = __expf(e1 - nm);
        float w2 = __expf(e2 - nm), w3 = __expf(e3 - nm);
        den = fmaf(den, sc, (w0 + w1) + (w2 + w3));
        a0 = fmaf(a0, sc, fmaf(w0, bflo(zz0), fmaf(w1, bflo(zz1), fmaf(w2, bflo(zz2), w3 * bflo(zz3)))));
        a1 = fmaf(a1, sc, fmaf(w0, bfhi(zz0), fmaf(w1, bfhi(zz1), fmaf(w2, bfhi(zz2), w3 * bfhi(zz3)))));
        m = nm;
    }
    for (; i + 1 < end; i += 2) {
        int s0 = esrc[i], s1 = esrc[i+1];
        float e0 = el[s0*16 + head] + ern;
        float e1 = el[s1*16 + head] + ern;
        int zz0 = *(const int*)(z + (size_t)s0*128 + c);
        int zz1 = *(const int*)(z + (size_t)s1*128 + c);
        e0 = (e0 > 0.f) ? e0 : 0.2f * e0;
        e1 = (e1 > 0.f) ? e1 : 0.2f * e1;
        float nm = fmaxf(m, fmaxf(e0, e1));
        float sc = __expf(m - nm);
        float w0 = __expf(e0 - nm);
        float w1 = __expf(e1 - nm);
        den = fmaf(den, sc, w0 + w1);
        a0  = fmaf(a0, sc, fmaf(w0, bflo(zz0), w1 * bflo(zz1)));
        a1  = fmaf(a1, sc, fmaf(w0, bfhi(zz0), w1 * bfhi(zz1)));
        m = nm;
    }
    if (i < end) {
        int s0 = esrc[i];
        float e0 = el[s0*16 + head] + ern;
        int zz0 = *(const int*)(z + (size_t)s0*128 + c);
        e0 = (e0 > 0.f) ? e0 : 0.2f * e0;
        float nm = fmaxf(m, e0);
        float sc = __expf(m - nm);
        float w0 = __expf(e0 - nm);
        den = fmaf(den, sc, w0);
        a0  = fmaf(a0, sc, w0 * bflo(zz0));
        a1  = fmaf(a1, sc, w0 * bfhi(zz0));
    }
    float inv = 1.f / den;
    size_t o = (size_t)gw*64 + lane;
    int hv = ((const int*)h)[o];
    float h0 = bflo(hv), h1 = bfhi(hv);
    if (hstats) {
        float mu0 = hstats[c] * invN;
        float v0  = hstats[128+c] * invN - mu0*mu0;
        float s0  = rsqrtf(v0 + 1e-5f) * hg[c];
        h0 = fmaf(h0 - mu0, s0, hb[c]);
        float mu1 = hstats[c+1] * invN;
        float v1  = hstats[128+c+1] * invN - mu1*mu1;
        float s1  = rsqrtf(v1 + 1e-5f) * hg[c+1];
        h1 = fmaf(h1 - mu1, s1, hb[c+1]);
    }
    float r0 = h0 + a0*inv + gbias[c];
    float r1 = h1 + a1*inv + gbias[c+1];
    ((int*)t1)[o] = pack2(r0, r1);
}

// ---------------- BatchNorm stats (for t1 after GAT) ----------------
__global__ __launch_bounds__(256) void bn_stats_k(const short* __restrict__ xin,
    float* __restrict__ stats, int Nn)
{
    __shared__ float s0s[256], s1s[256], q0s[256], q1s[256];
    int pair = threadIdx.x & 63;
    int slot = threadIdx.x >> 6;
    float s0 = 0.f, s1 = 0.f, q0 = 0.f, q1 = 0.f;
    for (int r = blockIdx.x*4 + slot; r < Nn; r += gridDim.x*4) {
        int v = *(const int*)(xin + (size_t)r*128 + pair*2);
        float a = bflo(v), b = bfhi(v);
        s0 += a; s1 += b;
        q0 = fmaf(a, a, q0); q1 = fmaf(b, b, q1);
    }
    s0s[threadIdx.x] = s0; s1s[threadIdx.x] = s1;
    q0s[threadIdx.x] = q0; q1s[threadIdx.x] = q1;
    __syncthreads();
    if (slot == 0) {
        #pragma unroll
        for (int j = 1; j < 4; ++j) {
            s0 += s0s[pair + j*64]; s1 += s1s[pair + j*64];
            q0 += q0s[pair + j*64]; q1 += q1s[pair + j*64];
        }
        atomicAdd(&stats[pair*2],       s0);
        atomicAdd(&stats[pair*2+1],     s1);
        atomicAdd(&stats[128+pair*2],   q0);
        atomicAdd(&stats[128+pair*2+1], q1);
    }
}

// ---------------- decoder output ----------------
__global__ __launch_bounds__(256) void dec_out_k(const short* __restrict__ udec,
    const float* __restrict__ W2, const float* __restrict__ b2,
    float* __restrict__ out, int Nn)
{
    int gw = (blockIdx.x * 256 + threadIdx.x) >> 6;
    if (gw >= Nn) return;
    int lane = threadIdx.x & 63;
    int v = ((const int*)(udec + (size_t)gw * 128))[lane];
    float p = bflo(v) * W2[lane*2] + bfhi(v) * W2[lane*2 + 1];
    #pragma unroll
    for (int off = 32; off > 0; off >>= 1) p += __shfl_down(p, off);
    if (lane == 0) out[gw] = p + b2[0];
}

extern "C" void kernel_launch(void* const* d_in, const int* in_sizes, int n_in,
                              void* d_out, int out_size, void* d_ws, size_t ws_size,
                              hipStream_t stream)
{
    const float* x      = (const float*)d_in[0];
    const int*   src    = (const int*)  d_in[1];
    const int*   dst    = (const int*)  d_in[2];
    const float* emb_W1 = (const float*)d_in[3];
    const float* emb_b1 = (const float*)d_in[4];
    const float* emb_W2 = (const float*)d_in[5];
    const float* emb_b2 = (const float*)d_in[6];
    const float* emb_Ws = (const float*)d_in[7];
    const float* emb_bs = (const float*)d_in[8];
    const float* gat_W  = (const float*)d_in[9];
    const float* gat_al = (const float*)d_in[10];
    const float* gat_ar = (const float*)d_in[11];
    const float* gat_b  = (const float*)d_in[12];
    const float* bn1_g  = (const float*)d_in[13];
    const float* bn1_b  = (const float*)d_in[14];
    const float* ff_W1  = (const float*)d_in[15];
    const float* ff_b1  = (const float*)d_in[16];
    const float* ff_W2  = (const float*)d_in[17];
    const float* ff_b2  = (const float*)d_in[18];
    const float* bn2_g  = (const float*)d_in[19];
    const float* bn2_b  = (const float*)d_in[20];
    const float* dec_W1 = (const float*)d_in[21];
    const float* dec_b1 = (const float*)d_in[22];
    const float* dec_W2 = (const float*)d_in[23];
    const float* dec_b2 = (const float*)d_in[24];
    float* out = (float*)d_out;
    (void)n_in; (void)out_size;

    const int N = in_sizes[0] / 2;
    const int E = in_sizes[1];
    const float invN = 1.f / (float)N;

    // ---- workspace ----
    char* p = (char*)d_ws;
    size_t used = 0;
    auto carve = [&](size_t bytes) {
        char* r = p; size_t a = (bytes + 255) & ~(size_t)255;
        p += a; used += a; return r;
    };
    const size_t nbH = (size_t)N * 128 * 2;
    short* xs[5];
    for (int i = 0; i < 5; ++i) xs[i] = (short*)carve(nbH);
    short* t1   = (short*)carve(nbH);
    char*  big  = (char*)carve(2 * nbH);
    int*   cnt    = (int*)carve((size_t)N * 4);
    float* stats8 = (float*)carve(8 * 256 * 4);
    int*   rowptr = (int*)carve((size_t)(N + 1) * 4);
    int*   wpos   = (int*)carve((size_t)N * 4);
    int*   esrc   = (int*)carve((size_t)E * 4);
    int*   bsum   = (int*)carve(256 * 4);
    short* emb_W2t = (short*)carve((size_t)128 * 128 * 2);
    short* gat_Wt  = (short*)carve((size_t)4 * 128 * 128 * 2);
    short* ff_W1t  = (short*)carve((size_t)4 * 128 * 256 * 2);
    short* ff_W2t  = (short*)carve((size_t)4 * 256 * 128 * 2);
    short* dec_W1t = (short*)carve((size_t)640 * 128 * 2);
    if (used > ws_size) return;

    short* u    = (short*)big;
    short* z    = (short*)big;
    float* el   = (float*)(big + nbH);
    float* er   = el + (size_t)N * 16;
    short* udec = (short*)big;

    dim3 b256(256);
    int ecb  = (E + 255) / 256;
    int nel2 = (N * 64 + 255) / 256;
    int gx   = (N + 127) / 128;
    int nwv  = (N + 3) / 4;
    int nb   = (N + 1023) / 1024;

    BN5 bn0;
    for (int i = 0; i < 5; ++i) { bn0.st[i] = nullptr; bn0.g[i] = nullptr; bn0.b[i] = nullptr; }
    bn0.stR = nullptr; bn0.gR = nullptr; bn0.bR = nullptr; bn0.invN = invN;

    // ---- weight convert + transpose ----
    wconv_k<<<dim3(64, 1), b256, 0, stream>>>(emb_W2, emb_W2t, 128, 128);
    wconv_k<<<dim3(64, 4), b256, 0, stream>>>(gat_W,  gat_Wt,  128, 128);
    wconv_k<<<dim3(128, 4), b256, 0, stream>>>(ff_W1, ff_W1t,  128, 256);
    wconv_k<<<dim3(128, 4), b256, 0, stream>>>(ff_W2, ff_W2t,  256, 128);
    wconv_k<<<dim3(320, 1), b256, 0, stream>>>(dec_W1, dec_W1t, 640, 128);

    // ---- zero cnt + 8 BN stats buffers ----
    {
        int ztot = (int)(((char*)(stats8 + 8*256) - (char*)cnt) / 4);
        zero_i32_k<<<(ztot + 255) / 256, b256, 0, stream>>>(cnt, ztot);
    }

    // ---- CSR build ----
    count_k<<<ecb, b256, 0, stream>>>(dst, cnt, E);
    scan_part_k<<<nb, b256, 0, stream>>>(cnt, bsum, N);
    scan_top_k<<<1, b256, 0, stream>>>(bsum, nb);
    scan_fin_k<<<nb, b256, 0, stream>>>(cnt, bsum, rowptr, wpos, N);
    scatter_k<<<ecb, b256, 0, stream>>>(src, dst, wpos, esrc, E);

    // ---- embed: xs0 = relu(x@W1+b1)@W2 + b2 + (x@Ws+bs) ----
    embed_k<<<nel2, b256, 0, stream>>>(x, emb_W1, emb_b1, emb_Ws, emb_bs, (int*)u, (int*)xs[0], N);
    gemm2_k<1,0,1,0><<<dim3(gx,1), b256, 0, stream>>>(u,u,u,u,u, 128, emb_W2t, 128,
        emb_b2, xs[0], nullptr, N, 128, bn0, nullptr, nullptr, nullptr, nullptr);

    for (int l = 0; l < 4; ++l) {
        float* st1 = stats8 + (size_t)(l*2)   * 256;
        float* st2 = stats8 + (size_t)(l*2+1) * 256;
        short* hl = xs[l];
        const float* hst = (l == 0) ? nullptr : stats8 + (size_t)((l-1)*2+1) * 256;
        const float* hgp = (l == 0) ? nullptr : bn2_g + (l-1)*128;
        const float* hbp = (l == 0) ? nullptr : bn2_b + (l-1)*128;

        // z = bn2(xs[l]) @ gatW[l]  (+ fused el/er)
        BN5 bz = bn0; bz.st[0] = hst; bz.g[0] = hgp; bz.b[0] = hbp;
        gemm2_k<1,0,0,1><<<dim3(gx,1), b256, 0, stream>>>(hl,hl,hl,hl,hl, 128,
            gat_Wt + (size_t)l*128*128, 128, nullptr, z, nullptr, N, 128, bz,
            gat_al + l*128, gat_ar + l*128, el, er);
        gat_k<<<nwv, b256, 0, stream>>>(hl, z, el, er, rowptr, esrc, gat_b + l*128, t1, N,
                                        hst, hgp, hbp, invN);
        bn_stats_k<<<400, b256, 0, stream>>>(t1, st1, N);
        // fused FF block: xs[l+1] = bn1(t1) + relu(bn1(t1)@W1+b1)@W2 + b2, stats -> st2
        ff_fused_k<<<gx, b256, 0, stream>>>(t1,
            ff_W1t + (size_t)l*128*256, ff_W2t + (size_t)l*256*128,
            ff_b1 + l*256, ff_b2 + l*128,
            st1, bn1_g + l*128, bn1_b + l*128, invN,
            xs[l+1], N, st2);
    }

    // ---- decoder: udec = relu(concat(xs0, bn2(t2_l)) @ dec_W1 + b1) ----
    BN5 bd = bn0;
    for (int k = 1; k < 5; ++k) {
        bd.st[k] = stats8 + (size_t)((k-1)*2+1) * 256;
        bd.g[k]  = bn2_g + (k-1)*128;
        bd.b[k]  = bn2_b + (k-1)*128;
    }
    gemm2_k<5,1,0,0><<<dim3(gx,1), b256, 0, stream>>>(xs[0], xs[1], xs[2], xs[3], xs[4], 128,
        dec_W1t, 640, dec_b1, udec, nullptr, N, 128, bd,
        nullptr, nullptr, nullptr, nullptr);
    dec_out_k<<<nwv, b256, 0, stream>>>(udec, dec_W2, dec_b2, out, N);
}